// Round 2
// baseline (320.837 us; speedup 1.0000x reference)
//
#include <hip/hip_runtime.h>
#include <hip/hip_bf16.h>
#include <math.h>

// Problem constants (from reference): VOCAB=50000, EMBED=256, MAXLEN=512,
// UNITS=32, F1=16, BATCH=512.
#define TT 512
#define BB 512
#define EE 256
#define UU 32
#define FF1 16

__device__ __forceinline__ void fma4(float4& a, float s, const float4& v) {
    a.x += s * v.x; a.y += s * v.y; a.z += s * v.z; a.w += s * v.w;
}
__device__ __forceinline__ void add4(float4& a, const float4& v) {
    a.x += v.x; a.y += v.y; a.z += v.z; a.w += v.w;
}

// ---------------------------------------------------------------------------
// Phase 1: Xp[t][b][u] = emb_table[tokens[b][t]] @ Wx + bias
// One thread computes TWO full rows (r0, r0+1) where r = t*BB + b.
// Wx (32 KB) staged in LDS, read as wave-uniform broadcast float4 (free).
// ---------------------------------------------------------------------------
__global__ __launch_bounds__(256) void phase1_xw(
    const int* __restrict__ tokens, const float* __restrict__ emb,
    const float* __restrict__ Wx, const float* __restrict__ bias,
    float* __restrict__ Xp)
{
    __shared__ float sWx[EE * UU];   // 8192 floats = 32 KB
    __shared__ float sB[UU];

    // cooperative stage of Wx (+ bias) into LDS
    {
        const float4* src = (const float4*)Wx;
        float4* dst = (float4*)sWx;
        #pragma unroll
        for (int i = 0; i < 8; ++i)
            dst[threadIdx.x + 256 * i] = src[threadIdx.x + 256 * i];
        if (threadIdx.x < UU) sB[threadIdx.x] = bias[threadIdx.x];
    }
    __syncthreads();

    const int gtid = blockIdx.x * 256 + threadIdx.x;
    const int r0 = gtid * 2;                 // rows r0 and r0+1
    const int t0 = r0 >> 9,       b0 = r0 & (BB - 1);
    const int t1 = (r0 + 1) >> 9, b1 = (r0 + 1) & (BB - 1);

    const int tok0 = tokens[b0 * TT + t0];
    const int tok1 = tokens[b1 * TT + t1];
    const float4* e0 = (const float4*)(emb + (size_t)tok0 * EE);
    const float4* e1 = (const float4*)(emb + (size_t)tok1 * EE);

    float4 acc0[8], acc1[8];
    #pragma unroll
    for (int j = 0; j < 8; ++j) {
        acc0[j] = make_float4(0.f, 0.f, 0.f, 0.f);
        acc1[j] = make_float4(0.f, 0.f, 0.f, 0.f);
    }

    const float4* w4 = (const float4*)sWx;
    for (int e4 = 0; e4 < EE / 4; ++e4) {    // 64 iterations
        float4 x0 = e0[e4];
        float4 x1 = e1[e4];
        const float4* wrow = w4 + e4 * 32;   // 4 rows of Wx, 8 float4 each
        #pragma unroll
        for (int j4 = 0; j4 < 8; ++j4) {
            float4 wa = wrow[j4];
            float4 wb = wrow[8 + j4];
            float4 wc = wrow[16 + j4];
            float4 wd = wrow[24 + j4];
            fma4(acc0[j4], x0.x, wa); fma4(acc0[j4], x0.y, wb);
            fma4(acc0[j4], x0.z, wc); fma4(acc0[j4], x0.w, wd);
            fma4(acc1[j4], x1.x, wa); fma4(acc1[j4], x1.y, wb);
            fma4(acc1[j4], x1.z, wc); fma4(acc1[j4], x1.w, wd);
        }
    }

    const float4* b4 = (const float4*)sB;
    #pragma unroll
    for (int j4 = 0; j4 < 8; ++j4) {
        float4 bq = b4[j4];
        add4(acc0[j4], bq);
        add4(acc1[j4], bq);
    }

    float4* o = (float4*)(Xp + (size_t)r0 * UU);  // 2 rows contiguous (256 B)
    #pragma unroll
    for (int j4 = 0; j4 < 8; ++j4) {
        o[j4]     = acc0[j4];
        o[8 + j4] = acc1[j4];
    }
}

// ---------------------------------------------------------------------------
// Phase 2: sequential scan h = tanh(Xp[t] + h @ Wh), then fused dense heads.
// 32 lanes per batch element (lane = unit). h broadcast via per-wave LDS.
// grid = 64 blocks x 256 threads (8 batch rows per block).
// ---------------------------------------------------------------------------
__global__ __launch_bounds__(256) void phase2_scan(
    const float* __restrict__ Xp, const float* __restrict__ Wh,
    const float* __restrict__ W1, const float* __restrict__ b1,
    const float* __restrict__ W2, const float* __restrict__ b2,
    float* __restrict__ out)
{
    __shared__ float hs[256];        // live h for this block's 8 rows
    __shared__ float hlast[8 * UU];
    __shared__ float y1[8 * FF1];

    const int u   = threadIdx.x & 31;
    const int row = threadIdx.x >> 5;
    const int b   = blockIdx.x * 8 + row;

    // preload this lane's Wh column: wh[k] = Wh[k][u]
    float wh[UU];
    #pragma unroll
    for (int k = 0; k < UU; ++k) wh[k] = Wh[k * UU + u];

    const float* xp = Xp + (size_t)b * UU + u;     // stride BB*UU per t
    const float4* hrow = (const float4*)(hs + row * UU);

    float h  = 0.f;
    float xv = xp[0];

    for (int t = 0; t < TT; ++t) {
        float xn = (t < TT - 1) ? xp[(size_t)(t + 1) * (BB * UU)] : 0.f;

        hs[threadIdx.x] = h;
        __builtin_amdgcn_wave_barrier();   // write before reads, within-wave
        float4 q0 = hrow[0], q1 = hrow[1], q2 = hrow[2], q3 = hrow[3];
        float4 q4 = hrow[4], q5 = hrow[5], q6 = hrow[6], q7 = hrow[7];
        __builtin_amdgcn_wave_barrier();   // reads before next iter's write

        float a0 = xv, a1 = 0.f, a2 = 0.f, a3 = 0.f;
        a0 += q0.x * wh[0];  a1 += q0.y * wh[1];  a2 += q0.z * wh[2];  a3 += q0.w * wh[3];
        a0 += q1.x * wh[4];  a1 += q1.y * wh[5];  a2 += q1.z * wh[6];  a3 += q1.w * wh[7];
        a0 += q2.x * wh[8];  a1 += q2.y * wh[9];  a2 += q2.z * wh[10]; a3 += q2.w * wh[11];
        a0 += q3.x * wh[12]; a1 += q3.y * wh[13]; a2 += q3.z * wh[14]; a3 += q3.w * wh[15];
        a0 += q4.x * wh[16]; a1 += q4.y * wh[17]; a2 += q4.z * wh[18]; a3 += q4.w * wh[19];
        a0 += q5.x * wh[20]; a1 += q5.y * wh[21]; a2 += q5.z * wh[22]; a3 += q5.w * wh[23];
        a0 += q6.x * wh[24]; a1 += q6.y * wh[25]; a2 += q6.z * wh[26]; a3 += q6.w * wh[27];
        a0 += q7.x * wh[28]; a1 += q7.y * wh[29]; a2 += q7.z * wh[30]; a3 += q7.w * wh[31];

        h  = tanhf((a0 + a1) + (a2 + a3));
        xv = xn;
    }

    hlast[row * UU + u] = h;
    __syncthreads();

    // y1[b][j] = hlast[b] . W1[:,j] + b1[j]   (128 threads)
    if (threadIdx.x < 8 * FF1) {
        const int bb = threadIdx.x >> 4;
        const int j  = threadIdx.x & 15;
        float s = b1[j];
        #pragma unroll
        for (int k = 0; k < UU; ++k)
            s += hlast[bb * UU + k] * W1[k * FF1 + j];
        y1[bb * FF1 + j] = s;
    }
    __syncthreads();

    // z[b] = y1[b] . W2 + b2 ; out = sigmoid(z)   (8 threads)
    if (threadIdx.x < 8) {
        float z = b2[0];
        #pragma unroll
        for (int j = 0; j < FF1; ++j)
            z += y1[threadIdx.x * FF1 + j] * W2[j];
        out[blockIdx.x * 8 + threadIdx.x] = 1.f / (1.f + expf(-z));
    }
}

// ---------------------------------------------------------------------------
extern "C" void kernel_launch(void* const* d_in, const int* in_sizes, int n_in,
                              void* d_out, int out_size, void* d_ws, size_t ws_size,
                              hipStream_t stream) {
    const int*   tokens = (const int*)  d_in[0];
    const float* emb    = (const float*)d_in[1];
    const float* Wx     = (const float*)d_in[2];
    const float* Wh     = (const float*)d_in[3];
    const float* bias   = (const float*)d_in[4];
    const float* W1     = (const float*)d_in[5];
    const float* b1     = (const float*)d_in[6];
    const float* W2     = (const float*)d_in[7];
    const float* b2     = (const float*)d_in[8];
    float* out = (float*)d_out;

    float* Xp = (float*)d_ws;   // needs T*B*U*4 = 33.5 MB of workspace

    // Phase 1: 262144 rows, 2 rows/thread -> 131072 threads -> 512 blocks
    phase1_xw<<<dim3(512), dim3(256), 0, stream>>>(tokens, emb, Wx, bias, Xp);

    // Phase 2: 512 batch rows, 8 per block -> 64 blocks
    phase2_scan<<<dim3(64), dim3(256), 0, stream>>>(Xp, Wh, W1, b1, W2, b2, out);
}

// Round 3
// 231.762 us; speedup vs baseline: 1.3843x; 1.3843x over previous
//
#include <hip/hip_runtime.h>
#include <hip/hip_bf16.h>
#include <math.h>

// VOCAB=50000, EMBED=256, MAXLEN=512, UNITS=32, F1=16, BATCH=512.
#define TT 512
#define BB 512
#define EE 256
#define UU 32
#define FF1 16

__device__ __forceinline__ void fma4(float4& a, float s, const float4& v) {
    a.x = fmaf(s, v.x, a.x); a.y = fmaf(s, v.y, a.y);
    a.z = fmaf(s, v.z, a.z); a.w = fmaf(s, v.w, a.w);
}

// tanh(x) = 1 - 2/(e^{2x}+1), branch-free. exp2/rcp are ~1-ulp HW approx.
// x->+inf: e=inf, r=0 -> 1.  x->-inf: e=0, r=1 -> -1.  No NaN for finite x.
__device__ __forceinline__ float fast_tanh(float x) {
    float e = __builtin_amdgcn_exp2f(x * 2.8853900817779268f);  // e^{2x}
    float r = __builtin_amdgcn_rcpf(e + 1.0f);
    return fmaf(-2.0f, r, 1.0f);
}

// ---------------------------------------------------------------------------
// Kernel A: P[v][u] = emb_table[v] @ Wx[:,u] + bias[u]   (vocab x 32)
// One thread per vocab row. Wx indices are wave-uniform -> scalar(K$)/L1
// broadcast loads; own-row reads are sequential float4 streaming.
// 0.82 GFLOP, 51.2 MB read, 6.4 MB write.
// ---------------------------------------------------------------------------
__global__ __launch_bounds__(128) void proj_vocab(
    const float* __restrict__ emb, const float* __restrict__ Wx,
    const float* __restrict__ bias, float* __restrict__ P, int nrows)
{
    const int r = blockIdx.x * 128 + threadIdx.x;
    if (r >= nrows) return;

    const float4* e = (const float4*)(emb + (size_t)r * EE);
    const float4* w4 = (const float4*)Wx;

    float4 acc[8];
    #pragma unroll
    for (int j = 0; j < 8; ++j) acc[j] = make_float4(0.f, 0.f, 0.f, 0.f);

    for (int k4 = 0; k4 < EE / 4; ++k4) {      // 64 iterations
        float4 x = e[k4];
        const float4* w = w4 + k4 * 32;        // 4 rows of Wx (uniform addr)
        #pragma unroll
        for (int j4 = 0; j4 < 8; ++j4) {
            float4 wa = w[j4];
            float4 wb = w[8 + j4];
            float4 wc = w[16 + j4];
            float4 wd = w[24 + j4];
            fma4(acc[j4], x.x, wa); fma4(acc[j4], x.y, wb);
            fma4(acc[j4], x.z, wc); fma4(acc[j4], x.w, wd);
        }
    }

    const float4* b4 = (const float4*)bias;
    float4* o = (float4*)(P + (size_t)r * UU);
    #pragma unroll
    for (int j4 = 0; j4 < 8; ++j4) {
        float4 bq = b4[j4];
        float4 a = acc[j4];
        a.x += bq.x; a.y += bq.y; a.z += bq.z; a.w += bq.w;
        o[j4] = a;
    }
}

// ---------------------------------------------------------------------------
// Kernel B: h_t = tanh(P[tok[b,t]] + h_{t-1} @ Wh); fused dense heads.
// 1 wave per block, 2 batch rows per wave (lane = unit within 32-lane half).
// h broadcast via LDS write + 8 broadcast ds_read_b128 (conflict-free).
// Latency-bound: 512 steps x (LDS roundtrip + 4-FMA chains + fast tanh).
// ---------------------------------------------------------------------------
__global__ __launch_bounds__(64) void scan_heads(
    const int* __restrict__ tokens, const float* __restrict__ P,
    const float* __restrict__ Wh,
    const float* __restrict__ W1, const float* __restrict__ b1,
    const float* __restrict__ W2, const float* __restrict__ b2,
    float* __restrict__ out)
{
    __shared__ float hs[64];
    __shared__ float y1s[2 * FF1];

    const int u    = threadIdx.x & 31;
    const int half = threadIdx.x >> 5;         // which of the 2 batch rows
    const int b    = blockIdx.x * 2 + half;

    // wh[k] = Wh[k][u] : this lane's column of the recurrent matrix
    float wh[UU];
    #pragma unroll
    for (int k = 0; k < UU; ++k) wh[k] = Wh[k * UU + u];

    const int* trow = tokens + b * TT;
    const float4* hrow = (const float4*)(hs + half * UU);

    // software pipeline: tok_n = token for step t+1; xv = x for step t
    int   tok_n = trow[1];
    float xv    = P[(size_t)trow[0] * UU + u];
    float h     = 0.f;

    for (int t = 0; t < TT; ++t) {
        // prefetch x for t+1 and token for t+2 (clamped) — off critical path
        float xn = P[(size_t)tok_n * UU + u];
        int tnext = t + 2 < TT ? t + 2 : TT - 1;
        int tok_nn = trow[tnext];

        hs[threadIdx.x] = h;
        __builtin_amdgcn_wave_barrier();       // write before reads (in-wave)
        float4 q0 = hrow[0], q1 = hrow[1], q2 = hrow[2], q3 = hrow[3];
        float4 q4 = hrow[4], q5 = hrow[5], q6 = hrow[6], q7 = hrow[7];
        __builtin_amdgcn_wave_barrier();       // reads before next write

        // 8 independent 4-FMA chains, then 3-level tree add
        float a0 = xv, a1 = 0.f, a2 = 0.f, a3 = 0.f;
        float a4 = 0.f, a5 = 0.f, a6 = 0.f, a7 = 0.f;
        a0 = fmaf(q0.x, wh[0],  a0); a0 = fmaf(q0.y, wh[1],  a0);
        a0 = fmaf(q0.z, wh[2],  a0); a0 = fmaf(q0.w, wh[3],  a0);
        a1 = fmaf(q1.x, wh[4],  a1); a1 = fmaf(q1.y, wh[5],  a1);
        a1 = fmaf(q1.z, wh[6],  a1); a1 = fmaf(q1.w, wh[7],  a1);
        a2 = fmaf(q2.x, wh[8],  a2); a2 = fmaf(q2.y, wh[9],  a2);
        a2 = fmaf(q2.z, wh[10], a2); a2 = fmaf(q2.w, wh[11], a2);
        a3 = fmaf(q3.x, wh[12], a3); a3 = fmaf(q3.y, wh[13], a3);
        a3 = fmaf(q3.z, wh[14], a3); a3 = fmaf(q3.w, wh[15], a3);
        a4 = fmaf(q4.x, wh[16], a4); a4 = fmaf(q4.y, wh[17], a4);
        a4 = fmaf(q4.z, wh[18], a4); a4 = fmaf(q4.w, wh[19], a4);
        a5 = fmaf(q5.x, wh[20], a5); a5 = fmaf(q5.y, wh[21], a5);
        a5 = fmaf(q5.z, wh[22], a5); a5 = fmaf(q5.w, wh[23], a5);
        a6 = fmaf(q6.x, wh[24], a6); a6 = fmaf(q6.y, wh[25], a6);
        a6 = fmaf(q6.z, wh[26], a6); a6 = fmaf(q6.w, wh[27], a6);
        a7 = fmaf(q7.x, wh[28], a7); a7 = fmaf(q7.y, wh[29], a7);
        a7 = fmaf(q7.z, wh[30], a7); a7 = fmaf(q7.w, wh[31], a7);

        float z = ((a0 + a1) + (a2 + a3)) + ((a4 + a5) + (a6 + a7));
        h = fast_tanh(z);

        xv = xn;
        tok_n = tok_nn;
    }

    // ---- fused heads (runs once; negligible) ----
    hs[threadIdx.x] = h;                       // hs[half*32 + u] = h_u
    __builtin_amdgcn_wave_barrier();
    __syncthreads();                           // 1 wave: cheap, safe

    if (threadIdx.x < 2 * FF1) {               // 32 threads: y1[row][j]
        const int row = threadIdx.x >> 4;
        const int j   = threadIdx.x & 15;
        float s = b1[j];
        #pragma unroll
        for (int k = 0; k < UU; ++k)
            s = fmaf(hs[row * UU + k], W1[k * FF1 + j], s);
        y1s[threadIdx.x] = s;
    }
    __syncthreads();

    if (threadIdx.x < 2) {                     // z[row] -> sigmoid
        float z = b2[0];
        #pragma unroll
        for (int j = 0; j < FF1; ++j)
            z = fmaf(y1s[threadIdx.x * FF1 + j], W2[j], z);
        float e = __builtin_amdgcn_exp2f(-z * 1.4426950408889634f); // e^{-z}
        out[blockIdx.x * 2 + threadIdx.x] = __builtin_amdgcn_rcpf(1.0f + e);
    }
}

// ---------------------------------------------------------------------------
extern "C" void kernel_launch(void* const* d_in, const int* in_sizes, int n_in,
                              void* d_out, int out_size, void* d_ws, size_t ws_size,
                              hipStream_t stream) {
    const int*   tokens = (const int*)  d_in[0];
    const float* emb    = (const float*)d_in[1];
    const float* Wx     = (const float*)d_in[2];
    const float* Wh     = (const float*)d_in[3];
    const float* bias   = (const float*)d_in[4];
    const float* W1     = (const float*)d_in[5];
    const float* b1     = (const float*)d_in[6];
    const float* W2     = (const float*)d_in[7];
    const float* b2     = (const float*)d_in[8];
    float* out = (float*)d_out;

    const int vocab = in_sizes[1] / EE;        // 50000
    float* P = (float*)d_ws;                   // vocab*32*4 = 6.4 MB

    proj_vocab<<<dim3((vocab + 127) / 128), dim3(128), 0, stream>>>(
        emb, Wx, bias, P, vocab);

    scan_heads<<<dim3(BB / 2), dim3(64), 0, stream>>>(
        tokens, P, Wh, W1, b1, W2, b2, out);
}

// Round 4
// 224.876 us; speedup vs baseline: 1.4267x; 1.0306x over previous
//
#include <hip/hip_runtime.h>
#include <hip/hip_bf16.h>
#include <math.h>

// VOCAB=50000, EMBED=256, MAXLEN=512, UNITS=32, F1=16, BATCH=512.
#define TT 512
#define BB 512
#define EE 256
#define UU 32
#define FF1 16

__device__ __forceinline__ void fma4(float4& a, float s, const float4& v) {
    a.x = fmaf(s, v.x, a.x); a.y = fmaf(s, v.y, a.y);
    a.z = fmaf(s, v.z, a.z); a.w = fmaf(s, v.w, a.w);
}

// tanh(x) = 1 - 2/(e^{2x}+1), branch-free (5 VALU instrs).
__device__ __forceinline__ float fast_tanh(float x) {
    float e = __builtin_amdgcn_exp2f(x * 2.8853900817779268f);  // e^{2x}
    float r = __builtin_amdgcn_rcpf(e + 1.0f);
    return fmaf(-2.0f, r, 1.0f);
}

__device__ __forceinline__ float rdlane(float v, int lane) {
    return __int_as_float(__builtin_amdgcn_readlane(__float_as_int(v), lane));
}

// ---------------------------------------------------------------------------
// Kernel A: P[v][u] = emb_table[v] @ Wx[:,u] + bias[u]   (vocab x 32)
// Wx staged in LDS (32 KB), read as wave-uniform broadcast ds_read_b128
// (conflict-free). 2 vocab rows per thread amortize the LDS reads.
// ---------------------------------------------------------------------------
__global__ __launch_bounds__(256) void proj_vocab(
    const float* __restrict__ emb, const float* __restrict__ Wx,
    const float* __restrict__ bias, float* __restrict__ P, int nrows)
{
    __shared__ float sWx[EE * UU];   // 8192 floats = 32 KB

    {   // cooperative stage of Wx into LDS
        const float4* src = (const float4*)Wx;
        float4* dst = (float4*)sWx;
        #pragma unroll
        for (int i = 0; i < 8; ++i)
            dst[threadIdx.x + 256 * i] = src[threadIdx.x + 256 * i];
    }
    __syncthreads();

    const int r0 = (blockIdx.x * 256 + threadIdx.x) * 2;  // rows r0, r0+1
    if (r0 >= nrows) return;                              // nrows is even

    const float4* e0 = (const float4*)(emb + (size_t)r0 * EE);
    const float4* e1 = (const float4*)(emb + (size_t)(r0 + 1) * EE);

    float4 acc0[8], acc1[8];
    #pragma unroll
    for (int j = 0; j < 8; ++j) {
        acc0[j] = make_float4(0.f, 0.f, 0.f, 0.f);
        acc1[j] = make_float4(0.f, 0.f, 0.f, 0.f);
    }

    const float4* w4 = (const float4*)sWx;
    for (int k4 = 0; k4 < EE / 4; ++k4) {    // 64 iterations
        float4 x0 = e0[k4];
        float4 x1 = e1[k4];
        const float4* w = w4 + k4 * 32;      // 4 rows of Wx, 8 float4 each
        #pragma unroll
        for (int j4 = 0; j4 < 8; ++j4) {
            float4 wa = w[j4];
            float4 wb = w[8 + j4];
            float4 wc = w[16 + j4];
            float4 wd = w[24 + j4];
            fma4(acc0[j4], x0.x, wa); fma4(acc0[j4], x0.y, wb);
            fma4(acc0[j4], x0.z, wc); fma4(acc0[j4], x0.w, wd);
            fma4(acc1[j4], x1.x, wa); fma4(acc1[j4], x1.y, wb);
            fma4(acc1[j4], x1.z, wc); fma4(acc1[j4], x1.w, wd);
        }
    }

    const float4* b4 = (const float4*)bias;
    float4* o = (float4*)(P + (size_t)r0 * UU);
    #pragma unroll
    for (int j4 = 0; j4 < 8; ++j4) {
        float4 bq = b4[j4];
        float4 a = acc0[j4], c = acc1[j4];
        a.x += bq.x; a.y += bq.y; a.z += bq.z; a.w += bq.w;
        c.x += bq.x; c.y += bq.y; c.z += bq.z; c.w += bq.w;
        o[j4]     = a;
        o[8 + j4] = c;
    }
}

// ---------------------------------------------------------------------------
// Kernel B: h_t = tanh(P[tok[b,t]] + h_{t-1} @ Wh); fused heads + sigmoid.
// ONE batch row per 64-lane wave; lane u (mod 32) owns unit u; both halves
// compute duplicates (no divergence, no cross-half traffic).
// h-broadcast via v_readlane -> SGPR operand of v_fma (NO LDS roundtrip:
// per-step critical path is pure VALU issue, ~155 cyc).
// P prefetched 4 steps deep (register ring, unroll-4) to cover L3 latency.
// ---------------------------------------------------------------------------
__global__ __launch_bounds__(64) void scan_heads(
    const int* __restrict__ tokens, const float* __restrict__ P,
    const float* __restrict__ Wh,
    const float* __restrict__ W1, const float* __restrict__ b1,
    const float* __restrict__ W2, const float* __restrict__ b2,
    float* __restrict__ out)
{
    const int u = threadIdx.x & 31;
    const int b = blockIdx.x;

    // wh[k] = Wh[k][u] : this lane's column of the recurrent matrix
    float wh[UU];
    #pragma unroll
    for (int k = 0; k < UU; ++k) wh[k] = Wh[k * UU + u];

    const int* trow = tokens + b * TT;

    // 4-deep software pipeline: xr[j] = x(t+j); tk[j] = token(t+4+j)
    float xr[4]; int tk[4];
    #pragma unroll
    for (int j = 0; j < 4; ++j) {
        xr[j] = P[(size_t)trow[j] * UU + u];
        tk[j] = trow[4 + j];
    }

    float h = 0.f;

    for (int t = 0; t < TT; t += 4) {
        #pragma unroll
        for (int j = 0; j < 4; ++j) {
            // prefetch x(t+j+4); token(t+j+8) (&-clamp: garbage-but-valid at tail)
            float xn = P[(size_t)tk[j] * UU + u];
            tk[j] = trow[(t + 8 + j) & (TT - 1)];

            // z_u = x_u + sum_k h_k * wh[k]; h_k broadcast via readlane (SGPR)
            float a0 = xr[j], a1 = 0.f, a2 = 0.f, a3 = 0.f;
            #pragma unroll
            for (int k = 0; k < UU; k += 4) {
                float h0 = rdlane(h, k);
                float h1 = rdlane(h, k + 1);
                float h2 = rdlane(h, k + 2);
                float h3 = rdlane(h, k + 3);
                a0 = fmaf(h0, wh[k],     a0);
                a1 = fmaf(h1, wh[k + 1], a1);
                a2 = fmaf(h2, wh[k + 2], a2);
                a3 = fmaf(h3, wh[k + 3], a3);
            }
            h = fast_tanh((a0 + a1) + (a2 + a3));
            xr[j] = xn;
        }
    }

    // ---- fused heads (once; readlane-only, no LDS) ----
    // lane j (mod 16) computes y1_j = b1[j] + sum_k h_k W1[k][j]
    const int j = threadIdx.x & 15;
    float s = b1[j];
    #pragma unroll
    for (int k = 0; k < UU; ++k) {
        float hk = rdlane(h, k);
        s = fmaf(hk, W1[k * FF1 + j], s);
    }
    // z = b2 + sum_j y1_j W2[j]  (y1_j lives in lane j)
    float z = b2[0];
    #pragma unroll
    for (int jj = 0; jj < FF1; ++jj) {
        float yj = rdlane(s, jj);
        z = fmaf(yj, W2[jj], z);
    }
    if (threadIdx.x == 0) {
        float e = __builtin_amdgcn_exp2f(-z * 1.4426950408889634f); // e^{-z}
        out[b] = __builtin_amdgcn_rcpf(1.0f + e);
    }
}

// ---------------------------------------------------------------------------
extern "C" void kernel_launch(void* const* d_in, const int* in_sizes, int n_in,
                              void* d_out, int out_size, void* d_ws, size_t ws_size,
                              hipStream_t stream) {
    const int*   tokens = (const int*)  d_in[0];
    const float* emb    = (const float*)d_in[1];
    const float* Wx     = (const float*)d_in[2];
    const float* Wh     = (const float*)d_in[3];
    const float* bias   = (const float*)d_in[4];
    const float* W1     = (const float*)d_in[5];
    const float* b1     = (const float*)d_in[6];
    const float* W2     = (const float*)d_in[7];
    const float* b2     = (const float*)d_in[8];
    float* out = (float*)d_out;

    const int vocab = in_sizes[1] / EE;        // 50000
    float* P = (float*)d_ws;                   // vocab*32*4 = 6.4 MB

    // 2 rows/thread, 512 rows/block -> 98 blocks
    proj_vocab<<<dim3((vocab + 511) / 512), dim3(256), 0, stream>>>(
        emb, Wx, bias, P, vocab);

    // 1 batch row per wave -> 512 blocks x 64 threads
    scan_heads<<<dim3(BB), dim3(64), 0, stream>>>(
        tokens, P, Wh, W1, b1, W2, b2, out);
}